// Round 4
// baseline (193.463 us; speedup 1.0000x reference)
//
#include <hip/hip_runtime.h>

typedef __bf16 bf16;
typedef __bf16 bf16x4 __attribute__((ext_vector_type(4)));
typedef __bf16 bf16x8 __attribute__((ext_vector_type(8)));
typedef float f32x4 __attribute__((ext_vector_type(4)));

#define MFMA16(a, b, c) __builtin_amdgcn_mfma_f32_16x16x32_bf16((a), (b), (c), 0, 0, 0)

// B=256, T=320, C=1024, H=64;  M = B*T = 81920
// ws (bf16): Wt [3][64][1024] | Qw [81920][64] | Kw [81920][64] | Vt [256][64][320]

// ---------------- Kernel 0: W -> Wt (bf16, [mat][h][k]) ----------------
__global__ __launch_bounds__(256) void wtrans_kernel(
    const float* __restrict__ Wk, const float* __restrict__ Wq,
    const float* __restrict__ Wv, bf16* __restrict__ Wt) {
  __shared__ bf16 tile[64][65];
  const int mat = blockIdx.x >> 4;
  const int kt = (blockIdx.x & 15) << 6;
  const float* __restrict__ W = (mat == 0) ? Wk : ((mat == 1) ? Wq : Wv);
  const int tid = threadIdx.x;
#pragma unroll
  for (int j = 0; j < 16; ++j) {
    const int i = tid + 256 * j;
    const int k = i >> 6, h = i & 63;
    tile[h][k] = (bf16)W[(kt + k) * 64 + h];
  }
  __syncthreads();
#pragma unroll
  for (int j = 0; j < 16; ++j) {
    const int i = tid + 256 * j;
    const int h = i >> 6, k = i & 63;
    Wt[mat * 65536 + h * 1024 + kt + k] = tile[h][k];
  }
}

// ---------------- Kernel 1: fused QKV projection ----------------
// 1280 blocks x 256 thr (4 waves). Block: 64 rows x 192 cols. Wave: 64x48.
// Double-buffered LDS, depth-2 global prefetch, one raw barrier per k-step,
// vmcnt never drained inside the loop.
__global__ __launch_bounds__(256) void qkv_kernel(
    const float* __restrict__ x, const bf16* __restrict__ Wt,
    bf16* __restrict__ Qw, bf16* __restrict__ Kw, bf16* __restrict__ Vt) {
  __shared__ bf16 xs[2][64][72];  // +8 pad: 2-way banks on b128 reads (free)
  const int tid = threadIdx.x;
  const int w = tid >> 6, l = tid & 63;
  const int lr = l & 15, lg = l >> 4;
  const int m0 = blockIdx.x * 64;

  f32x4 acc[4][3];
#pragma unroll
  for (int mf = 0; mf < 4; ++mf)
#pragma unroll
    for (int nf = 0; nf < 3; ++nf) acc[mf][nf] = (f32x4)0.0f;

  float4 gA[4], gB[4];
  bf16x8 wf[3][2], wn[3][2];

  auto loadx = [&](int kt, float4* gg) {
#pragma unroll
    for (int j = 0; j < 4; ++j) {
      const int u = tid + 256 * j;
      gg[j] = *(const float4*)(x + (size_t)(m0 + (u >> 4)) * 1024 + kt + (u & 15) * 4);
    }
  };
  auto loadw = [&](int kt, bf16x8 wfr[3][2]) {
#pragma unroll
    for (int nf = 0; nf < 3; ++nf) {
      const int colg = w * 48 + nf * 16 + lr;  // frag never straddles a matrix
      const bf16* p = Wt + (colg >> 6) * 65536 + (colg & 63) * 1024 + kt + lg * 8;
      wfr[nf][0] = *(const bf16x8*)p;
      wfr[nf][1] = *(const bf16x8*)(p + 32);
    }
  };
  auto step = [&](int t, float4* gg, bf16x8 wu[3][2], bf16x8 wp[3][2]) {
    // fp32 regs -> bf16 LDS (compiler emits counted vmcnt wait for gg)
#pragma unroll
    for (int j = 0; j < 4; ++j) {
      const int u = tid + 256 * j;
      bf16x4 h4;
      h4[0] = (bf16)gg[j].x; h4[1] = (bf16)gg[j].y;
      h4[2] = (bf16)gg[j].z; h4[3] = (bf16)gg[j].w;
      *(bf16x4*)(&xs[t & 1][u >> 4][(u & 15) * 4]) = h4;
    }
    if (t + 2 < 16) loadx((t + 2) * 64, gg);  // depth-2: spans 2 barriers
    asm volatile("s_waitcnt lgkmcnt(0)" ::: "memory");  // ds_writes visible
    __builtin_amdgcn_sched_barrier(0);
    __builtin_amdgcn_s_barrier();  // raw barrier: vmcnt NOT drained
    __builtin_amdgcn_sched_barrier(0);
    if (t + 1 < 16) loadw((t + 1) * 64, wp);  // prefetch next W frags (L2-hit)
#pragma unroll
    for (int mf = 0; mf < 4; ++mf) {
      const bf16x8 a0 = *(const bf16x8*)(&xs[t & 1][mf * 16 + lr][lg * 8]);
      const bf16x8 a1 = *(const bf16x8*)(&xs[t & 1][mf * 16 + lr][32 + lg * 8]);
#pragma unroll
      for (int nf = 0; nf < 3; ++nf) {
        acc[mf][nf] = MFMA16(a0, wu[nf][0], acc[mf][nf]);
        acc[mf][nf] = MFMA16(a1, wu[nf][1], acc[mf][nf]);
      }
    }
    // no second barrier: next step writes the other buffer
  };

  loadx(0, gA);
  loadx(64, gB);
  loadw(0, wf);
#pragma unroll
  for (int t2 = 0; t2 < 16; t2 += 2) {
    step(t2, gA, wf, wn);      // consume wf, prefetch wn
    step(t2 + 1, gB, wn, wf);  // consume wn, prefetch wf
  }

  // epilogue: C[i=A-row][j=B-row]; i=(lane>>4)*4+r, j=lane&15
#pragma unroll
  for (int mf = 0; mf < 4; ++mf) {
#pragma unroll
    for (int nf = 0; nf < 3; ++nf) {
      const int colg = w * 48 + nf * 16 + lr;
      const int mat = colg >> 6, h = colg & 63;
      const int mb = m0 + mf * 16 + lg * 4;  // 64 | 320: block within one batch
      if (mat == 2) {  // V transposed [b][h][t]
        const int b = mb / 320, t = mb % 320;
        bf16x4 o;
#pragma unroll
        for (int r = 0; r < 4; ++r) o[r] = (bf16)acc[mf][nf][r];
        *(bf16x4*)(Vt + ((size_t)b * 64 + h) * 320 + t) = o;
      } else {
        bf16* __restrict__ dst = (mat == 0) ? Kw : Qw;
#pragma unroll
        for (int r = 0; r < 4; ++r) dst[(size_t)(mb + r) * 64 + h] = (bf16)acc[mf][nf][r];
      }
    }
  }
}

// ---------------- Kernel 2: causal attention, swapped QK^T ----------------
// S^T = mfma(A=K, B=Q): lane holds q-row t=lane&15, s = nf*16+(lane>>4)*4+r.
// Per-wave causal fragment count; heavy qt dispatched first.
__global__ __launch_bounds__(256) void attn_kernel(
    const bf16* __restrict__ Qw, const bf16* __restrict__ Kw,
    const bf16* __restrict__ Vt, float* __restrict__ out) {
  constexpr int PSTR = 332;  // bank stride 6 -> 16 distinct banks
  __shared__ bf16 Pl[4 * 16 * PSTR];
  const int b = blockIdx.x;          // id%8 == b%8: all qt of b on one XCD
  const int qt = 4 - blockIdx.y;     // heavy blocks dispatch first
  const int tid = threadIdx.x;
  const int w = tid >> 6, l = tid & 63;
  const int lr = l & 15, lg = l >> 4;
  const int qi = qt * 4 + w;         // this wave's 16-row q-tile, 0..19
  const int t0 = qi * 16;
  const int nfmax = qi + 1;          // live 16-wide s-fragments (causal)
  const int tq = t0 + lr;

  // Q as B-fragments (col = q row tq)
  const bf16* qp = Qw + ((size_t)b * 320 + tq) * 64 + lg * 8;
  const bf16x8 bq0 = *(const bf16x8*)qp;
  const bf16x8 bq1 = *(const bf16x8*)(qp + 32);

  // S^T: A = K rows (s), B = Q rows (t)
  f32x4 acs[20];
  const bf16* kb = Kw + ((size_t)b * 320 + lr) * 64 + lg * 8;
#pragma unroll
  for (int nf = 0; nf < 20; ++nf) {
    if (nf >= nfmax) break;
    const bf16x8 a0 = *(const bf16x8*)(kb + nf * 1024);
    const bf16x8 a1 = *(const bf16x8*)(kb + nf * 1024 + 32);
    f32x4 a = (f32x4)0.0f;
    a = MFMA16(a0, bq0, a);
    a = MFMA16(a1, bq1, a);
    acs[nf] = a;
  }

  // scale 1/32, causal mask, softmax over s (lane-local + 2 shuffles)
  float mx = -1e30f;
#pragma unroll
  for (int nf = 0; nf < 20; ++nf) {
    if (nf >= nfmax) break;
#pragma unroll
    for (int r = 0; r < 4; ++r) {
      const int sg = nf * 16 + lg * 4 + r;
      float v = acs[nf][r] * 0.03125f;
      v = (sg > tq) ? -1e30f : v;
      acs[nf][r] = v;
      mx = fmaxf(mx, v);
    }
  }
  mx = fmaxf(mx, __shfl_xor(mx, 16));
  mx = fmaxf(mx, __shfl_xor(mx, 32));
  float sum = 0.f;
#pragma unroll
  for (int nf = 0; nf < 20; ++nf) {
    if (nf >= nfmax) break;
#pragma unroll
    for (int r = 0; r < 4; ++r) {
      const float p = __expf(acs[nf][r] - mx);
      acs[nf][r] = p;
      sum += p;
    }
  }
  sum += __shfl_xor(sum, 16);
  sum += __shfl_xor(sum, 32);
  const float rinv = 1.0f / sum;

  // normalized P -> wave-private LDS, b64 packed (r contiguous in s)
  bf16* Pw = Pl + w * (16 * PSTR);
#pragma unroll
  for (int nf = 0; nf < 20; ++nf) {
    if (nf >= nfmax) break;
    bf16x4 o;
#pragma unroll
    for (int r = 0; r < 4; ++r) o[r] = (bf16)(acs[nf][r] * rinv);
    *(bf16x4*)(Pw + lr * PSTR + nf * 16 + lg * 4) = o;
  }
  if (nfmax & 1) {  // zero odd 16-col tail so last 32-wide PV step is clean
    bf16x4 z;
    z[0] = z[1] = z[2] = z[3] = (bf16)0.0f;
    *(bf16x4*)(Pw + lr * PSTR + nfmax * 16 + lg * 4) = z;
  }

  // O = P V  (A = P rows t, B = Vt rows h, k = s)
  const int ksmax = (nfmax + 1) >> 1;
  f32x4 ao[4];
#pragma unroll
  for (int hf = 0; hf < 4; ++hf) ao[hf] = (f32x4)0.0f;
  const bf16* vb = Vt + ((size_t)b * 64 + lr) * 320 + lg * 8;
#pragma unroll
  for (int ks = 0; ks < 10; ++ks) {
    if (ks >= ksmax) break;
    const bf16x8 ap = *(const bf16x8*)(Pw + lr * PSTR + ks * 32 + lg * 8);
#pragma unroll
    for (int hf = 0; hf < 4; ++hf) {
      const bf16x8 bv = *(const bf16x8*)(vb + hf * 16 * 320 + ks * 32);
      ao[hf] = MFMA16(ap, bv, ao[hf]);
    }
  }
  const int rowb = t0 + lg * 4;
#pragma unroll
  for (int hf = 0; hf < 4; ++hf)
#pragma unroll
    for (int r = 0; r < 4; ++r)
      out[((size_t)b * 320 + rowb + r) * 64 + hf * 16 + lr] = ao[hf][r];
}

extern "C" void kernel_launch(void* const* d_in, const int* in_sizes, int n_in,
                              void* d_out, int out_size, void* d_ws, size_t ws_size,
                              hipStream_t stream) {
  const float* x  = (const float*)d_in[0];
  const float* Wk = (const float*)d_in[1];
  const float* Wq = (const float*)d_in[2];
  const float* Wv = (const float*)d_in[3];
  float* out = (float*)d_out;

  bf16* Wt = (bf16*)d_ws;
  bf16* Qw = Wt + 3 * 64 * 1024;
  bf16* Kw = Qw + (size_t)81920 * 64;
  bf16* Vt = Kw + (size_t)81920 * 64;

  hipLaunchKernelGGL(wtrans_kernel, dim3(48), dim3(256), 0, stream, Wk, Wq, Wv, Wt);
  hipLaunchKernelGGL(qkv_kernel, dim3(1280), dim3(256), 0, stream, x, Wt, Qw, Kw, Vt);
  hipLaunchKernelGGL(attn_kernel, dim3(256, 5), dim3(256), 0, stream, Qw, Kw, Vt, out);
}

// Round 5
// 135.335 us; speedup vs baseline: 1.4295x; 1.4295x over previous
//
#include <hip/hip_runtime.h>

typedef __bf16 bf16;
typedef __bf16 bf16x4 __attribute__((ext_vector_type(4)));
typedef __bf16 bf16x8 __attribute__((ext_vector_type(8)));
typedef float f32x4 __attribute__((ext_vector_type(4)));

#define MFMA16(a, b, c) __builtin_amdgcn_mfma_f32_16x16x32_bf16((a), (b), (c), 0, 0, 0)

// global -> LDS DMA, 16B per lane; LDS dest is wave-uniform base + lane*16.
#define GLD16(gp, lp)                                                              \
  __builtin_amdgcn_global_load_lds(                                                \
      (const __attribute__((address_space(1))) unsigned int*)(unsigned long long)(gp), \
      (__attribute__((address_space(3))) unsigned int*)(unsigned long long)(lp), 16, 0, 0)

// B=256, T=320, C=1024, H=64;  M = B*T = 81920
// ws (bf16): Wt [3][64][1024] | Qw [81920][64] | Kw [81920][64] | Vt [256][64][320]

// ---------------- Kernel 0: W -> Wt (bf16, [mat][h][k]) ----------------
__global__ __launch_bounds__(256) void wtrans_kernel(
    const float* __restrict__ Wk, const float* __restrict__ Wq,
    const float* __restrict__ Wv, bf16* __restrict__ Wt) {
  __shared__ bf16 tile[64][65];
  const int mat = blockIdx.x >> 4;
  const int kt = (blockIdx.x & 15) << 6;
  const float* __restrict__ W = (mat == 0) ? Wk : ((mat == 1) ? Wq : Wv);
  const int tid = threadIdx.x;
#pragma unroll
  for (int j = 0; j < 16; ++j) {
    const int i = tid + 256 * j;
    const int k = i >> 6, h = i & 63;
    tile[h][k] = (bf16)W[(kt + k) * 64 + h];
  }
  __syncthreads();
#pragma unroll
  for (int j = 0; j < 16; ++j) {
    const int i = tid + 256 * j;
    const int h = i >> 6, k = i & 63;
    Wt[mat * 65536 + h * 1024 + kt + k] = tile[h][k];
  }
}

// ---------------- Kernel 1: fused QKV projection, global_load_lds staging ----------------
// 1280 blocks x 256 thr (4 waves). Block: 64 rows x 192 cols. Wave: 64x48.
// x staged as fp32 via DMA into 3 LDS buffers (depth-2), counted vmcnt, one raw
// barrier per step, zero ds_writes. Source-side XOR swizzle (rule 21: linear
// dest + pre-swizzled global src + swizzled read).
__global__ __launch_bounds__(256) void qkv_kernel(
    const float* __restrict__ x, const bf16* __restrict__ Wt,
    bf16* __restrict__ Qw, bf16* __restrict__ Kw, bf16* __restrict__ Vt) {
  __shared__ float xs3[3][64][64];  // 48 KB
  const int tid = threadIdx.x;
  const int w = tid >> 6, l = tid & 63;
  const int lr = l & 15, lg = l >> 4;
  const int m0 = blockIdx.x * 64;

  f32x4 acc[4][3];
#pragma unroll
  for (int mf = 0; mf < 4; ++mf)
#pragma unroll
    for (int nf = 0; nf < 3; ++nf) acc[mf][nf] = (f32x4)0.0f;

  // Per-lane DMA source bases (swizzled column), constant across k-steps.
  // Instr j covers tile rows 16w+4j .. +3; lane supplies 16B chunk (l&15),
  // row offset (l>>4); source col XORed so a linear DMA write + XORed read
  // reconstruct the swizzle (involution).
  const char* gb0;
  const char* gb1;
  const char* gb2;
  const char* gb3;
  {
    const int rr = l >> 4;
    const int cb = (l & 15) * 16;
    gb0 = (const char*)(x + (size_t)(m0 + 16 * w + 0 + rr) * 1024) + (cb ^ (((0 + rr) & 7) << 4));
    gb1 = (const char*)(x + (size_t)(m0 + 16 * w + 4 + rr) * 1024) + (cb ^ (((4 + rr) & 7) << 4));
    gb2 = (const char*)(x + (size_t)(m0 + 16 * w + 8 + rr) * 1024) + (cb ^ (((0 + rr) & 7) << 4));
    gb3 = (const char*)(x + (size_t)(m0 + 16 * w + 12 + rr) * 1024) + (cb ^ (((4 + rr) & 7) << 4));
  }

  bf16x8 wf[3][2];
  auto loadw = [&](int kt) {
#pragma unroll
    for (int nf = 0; nf < 3; ++nf) {
      const int colg = w * 48 + nf * 16 + lr;  // frag never straddles a matrix
      const bf16* p = Wt + (colg >> 6) * 65536 + (colg & 63) * 1024 + kt + lg * 8;
      wf[nf][0] = *(const bf16x8*)p;
      wf[nf][1] = *(const bf16x8*)(p + 32);
    }
  };
  auto dma = [&](int t) {  // 4 instrs: tile t (16 KB) -> buffer t%3; lds dest wave-uniform
    char* lb = (char*)&xs3[t % 3][16 * w][0];
    const int ko = t * 256;  // 64 fp32 k-cols
    GLD16(gb0 + ko, lb + 0 * 1024);
    GLD16(gb1 + ko, lb + 1 * 1024);
    GLD16(gb2 + ko, lb + 2 * 1024);
    GLD16(gb3 + ko, lb + 3 * 1024);
  };

  dma(0);
  dma(1);
  const int sw = (lr & 7) << 4;
#pragma unroll
  for (int t = 0; t < 16; ++t) {
    // Tile t's 4 DMAs are this wave's oldest outstanding VMEM; leave tile t+1 in flight.
    if (t < 15) {
      asm volatile("s_waitcnt vmcnt(4)" ::: "memory");
    } else {
      asm volatile("s_waitcnt vmcnt(0)" ::: "memory");
    }
    __builtin_amdgcn_sched_barrier(0);
    __builtin_amdgcn_s_barrier();  // all waves verified their tile-t DMAs
    __builtin_amdgcn_sched_barrier(0);
    loadw(t * 64);            // issued BEFORE dma(t+2): waiting wf won't force it
    if (t < 14) dma(t + 2);   // buffer (t+2)%3 held tile t-1: reads done pre-barrier
    const char* xb = (const char*)&xs3[t % 3][0][0];
#pragma unroll
    for (int mf = 0; mf < 4; ++mf) {
      const char* rp = xb + (mf * 16 + lr) * 256;
      const f32x4 f0 = *(const f32x4*)(rp + ((lg * 32 + 0) ^ sw));
      const f32x4 f1 = *(const f32x4*)(rp + ((lg * 32 + 16) ^ sw));
      const f32x4 f2 = *(const f32x4*)(rp + (128 + ((lg * 32 + 0) ^ sw)));
      const f32x4 f3 = *(const f32x4*)(rp + (128 + ((lg * 32 + 16) ^ sw)));
      bf16x8 a0, a1;
#pragma unroll
      for (int j = 0; j < 4; ++j) {
        a0[j] = (bf16)f0[j]; a0[4 + j] = (bf16)f1[j];
        a1[j] = (bf16)f2[j]; a1[4 + j] = (bf16)f3[j];
      }
#pragma unroll
      for (int nf = 0; nf < 3; ++nf) {
        acc[mf][nf] = MFMA16(a0, wf[nf][0], acc[mf][nf]);
        acc[mf][nf] = MFMA16(a1, wf[nf][1], acc[mf][nf]);
      }
    }
  }

  // epilogue: C[i=A-row][j=B-row]; i=(lane>>4)*4+r, j=lane&15
#pragma unroll
  for (int mf = 0; mf < 4; ++mf) {
#pragma unroll
    for (int nf = 0; nf < 3; ++nf) {
      const int colg = w * 48 + nf * 16 + lr;
      const int mat = colg >> 6, h = colg & 63;
      const int mb = m0 + mf * 16 + lg * 4;  // 64 | 320: block within one batch
      if (mat == 2) {  // V transposed [b][h][t]
        const int b = mb / 320, t = mb % 320;
        bf16x4 o;
#pragma unroll
        for (int r = 0; r < 4; ++r) o[r] = (bf16)acc[mf][nf][r];
        *(bf16x4*)(Vt + ((size_t)b * 64 + h) * 320 + t) = o;
      } else {
        bf16* __restrict__ dst = (mat == 0) ? Kw : Qw;
#pragma unroll
        for (int r = 0; r < 4; ++r) dst[(size_t)(mb + r) * 64 + h] = (bf16)acc[mf][nf][r];
      }
    }
  }
}

// ---------------- Kernel 2: causal attention (exact round-2 version) ----------------
// S^T = mfma(A=K, B=Q): lane holds q-row t=lane&15, s = nf*16 + (lane>>4)*4 + r.
template <int QT>
__device__ __forceinline__ void attn_impl(
    int b, const bf16* __restrict__ Qw, const bf16* __restrict__ Kw,
    const bf16* __restrict__ Vt, float* __restrict__ out, bf16* Pl) {
  constexpr int NF = 4 * (QT + 1);  // live 16-wide s fragments (causal)
  constexpr int KS = 2 * (QT + 1);  // 32-wide k-steps for PV
  constexpr int PSTR = 332;         // bank stride 6 -> 16 distinct banks
  const int tid = threadIdx.x;
  const int w = tid >> 6, l = tid & 63;
  const int lr = l & 15, lg = l >> 4;
  const int t0 = QT * 64 + w * 16;

  // Q as B-fragments (col = q row t0+lr)
  const bf16* qp = Qw + ((size_t)b * 320 + t0 + lr) * 64 + lg * 8;
  const bf16x8 bq0 = *(const bf16x8*)qp;
  const bf16x8 bq1 = *(const bf16x8*)(qp + 32);

  f32x4 acc[NF];
#pragma unroll
  for (int nf = 0; nf < NF; ++nf) acc[nf] = (f32x4)0.0f;

  // S^T: A = K rows (s), B = Q rows (t)
  const bf16* kb = Kw + ((size_t)b * 320 + lr) * 64 + lg * 8;
#pragma unroll
  for (int nf = 0; nf < NF; ++nf) {
    const bf16x8 a0 = *(const bf16x8*)(kb + nf * 1024);
    const bf16x8 a1 = *(const bf16x8*)(kb + nf * 1024 + 32);
    acc[nf] = MFMA16(a0, bq0, acc[nf]);
    acc[nf] = MFMA16(a1, bq1, acc[nf]);
  }

  // scale 1/32, causal mask, softmax over s (lane-local + 2 shuffles)
  const int tg = t0 + lr;
  float mx = -1e30f;
#pragma unroll
  for (int nf = 0; nf < NF; ++nf)
#pragma unroll
    for (int r = 0; r < 4; ++r) {
      const int sg = nf * 16 + lg * 4 + r;
      float v = acc[nf][r] * 0.03125f;
      v = (sg > tg) ? -1e30f : v;
      acc[nf][r] = v;
      mx = fmaxf(mx, v);
    }
  mx = fmaxf(mx, __shfl_xor(mx, 16));
  mx = fmaxf(mx, __shfl_xor(mx, 32));
  float sum = 0.f;
#pragma unroll
  for (int nf = 0; nf < NF; ++nf)
#pragma unroll
    for (int r = 0; r < 4; ++r) {
      const float p = __expf(acc[nf][r] - mx);
      acc[nf][r] = p;
      sum += p;
    }
  sum += __shfl_xor(sum, 16);
  sum += __shfl_xor(sum, 32);
  const float rinv = 1.0f / sum;

  // normalized P -> wave-private LDS, b64 packed (r contiguous in s)
  bf16* Pw = Pl + w * (16 * PSTR);
#pragma unroll
  for (int nf = 0; nf < NF; ++nf) {
    bf16x4 o;
#pragma unroll
    for (int r = 0; r < 4; ++r) o[r] = (bf16)(acc[nf][r] * rinv);
    *(bf16x4*)(Pw + lr * PSTR + nf * 16 + lg * 4) = o;
  }

  // O = P V  (A = P rows t, B = Vt rows h, k = s)
  f32x4 ao[4];
#pragma unroll
  for (int hf = 0; hf < 4; ++hf) ao[hf] = (f32x4)0.0f;
  const bf16* vb = Vt + ((size_t)b * 64 + lr) * 320 + lg * 8;
#pragma unroll
  for (int ks = 0; ks < KS; ++ks) {
    const bf16x8 ap = *(const bf16x8*)(Pw + lr * PSTR + ks * 32 + lg * 8);
#pragma unroll
    for (int hf = 0; hf < 4; ++hf) {
      const bf16x8 bv = *(const bf16x8*)(vb + hf * 16 * 320 + ks * 32);
      ao[hf] = MFMA16(ap, bv, ao[hf]);
    }
  }
  const int rowb = t0 + lg * 4;
#pragma unroll
  for (int hf = 0; hf < 4; ++hf)
#pragma unroll
    for (int r = 0; r < 4; ++r)
      out[((size_t)b * 320 + rowb + r) * 64 + hf * 16 + lr] = ao[hf][r];
}

__global__ __launch_bounds__(256) void attn_kernel(
    const bf16* __restrict__ Qw, const bf16* __restrict__ Kw,
    const bf16* __restrict__ Vt, float* __restrict__ out) {
  __shared__ bf16 Pl[4 * 16 * 332];  // 42.5 KB -> 3 blocks/CU
  const int b = blockIdx.x;   // id%8 == b%8: all qt of b on one XCD
  const int qt = blockIdx.y;  // 0..4
  switch (qt) {
    case 0: attn_impl<0>(b, Qw, Kw, Vt, out, Pl); break;
    case 1: attn_impl<1>(b, Qw, Kw, Vt, out, Pl); break;
    case 2: attn_impl<2>(b, Qw, Kw, Vt, out, Pl); break;
    case 3: attn_impl<3>(b, Qw, Kw, Vt, out, Pl); break;
    default: attn_impl<4>(b, Qw, Kw, Vt, out, Pl); break;
  }
}

extern "C" void kernel_launch(void* const* d_in, const int* in_sizes, int n_in,
                              void* d_out, int out_size, void* d_ws, size_t ws_size,
                              hipStream_t stream) {
  const float* x  = (const float*)d_in[0];
  const float* Wk = (const float*)d_in[1];
  const float* Wq = (const float*)d_in[2];
  const float* Wv = (const float*)d_in[3];
  float* out = (float*)d_out;

  bf16* Wt = (bf16*)d_ws;
  bf16* Qw = Wt + 3 * 64 * 1024;
  bf16* Kw = Qw + (size_t)81920 * 64;
  bf16* Vt = Kw + (size_t)81920 * 64;

  hipLaunchKernelGGL(wtrans_kernel, dim3(48), dim3(256), 0, stream, Wk, Wq, Wv, Wt);
  hipLaunchKernelGGL(qkv_kernel, dim3(1280), dim3(256), 0, stream, x, Wt, Qw, Kw, Vt);
  hipLaunchKernelGGL(attn_kernel, dim3(256, 5), dim3(256), 0, stream, Qw, Kw, Vt, out);
}

// Round 6
// 119.149 us; speedup vs baseline: 1.6237x; 1.1359x over previous
//
#include <hip/hip_runtime.h>

typedef __bf16 bf16;
typedef __bf16 bf16x4 __attribute__((ext_vector_type(4)));
typedef __bf16 bf16x8 __attribute__((ext_vector_type(8)));
typedef float f32x4 __attribute__((ext_vector_type(4)));

#define MFMA16(a, b, c) __builtin_amdgcn_mfma_f32_16x16x32_bf16((a), (b), (c), 0, 0, 0)

// global -> LDS DMA, 16B per lane; LDS dest is wave-uniform base + lane*16.
#define GLD16(gp, lp)                                                              \
  __builtin_amdgcn_global_load_lds(                                                \
      (const __attribute__((address_space(1))) unsigned int*)(unsigned long long)(gp), \
      (__attribute__((address_space(3))) unsigned int*)(unsigned long long)(lp), 16, 0, 0)

// B=256, T=320, C=1024, H=64;  M = B*T = 81920
// ws (bf16): Wt [3][64][1024] | Qw [81920][64] | Kw [81920][64] | Vt [256][64][320]

// ---------------- Kernel 0: W -> Wt (bf16, [mat][h][k]) ----------------
__global__ __launch_bounds__(256) void wtrans_kernel(
    const float* __restrict__ Wk, const float* __restrict__ Wq,
    const float* __restrict__ Wv, bf16* __restrict__ Wt) {
  __shared__ bf16 tile[64][65];
  const int mat = blockIdx.x >> 4;
  const int kt = (blockIdx.x & 15) << 6;
  const float* __restrict__ W = (mat == 0) ? Wk : ((mat == 1) ? Wq : Wv);
  const int tid = threadIdx.x;
#pragma unroll
  for (int j = 0; j < 16; ++j) {
    const int i = tid + 256 * j;
    const int k = i >> 6, h = i & 63;
    tile[h][k] = (bf16)W[(kt + k) * 64 + h];
  }
  __syncthreads();
#pragma unroll
  for (int j = 0; j < 16; ++j) {
    const int i = tid + 256 * j;
    const int h = i >> 6, k = i & 63;
    Wt[mat * 65536 + h * 1024 + kt + k] = tile[h][k];
  }
}

// ---------------- Kernel 1: fused QKV projection (exact round-5 version) ----------------
__global__ __launch_bounds__(256) void qkv_kernel(
    const float* __restrict__ x, const bf16* __restrict__ Wt,
    bf16* __restrict__ Qw, bf16* __restrict__ Kw, bf16* __restrict__ Vt) {
  __shared__ float xs3[3][64][64];  // 48 KB
  const int tid = threadIdx.x;
  const int w = tid >> 6, l = tid & 63;
  const int lr = l & 15, lg = l >> 4;
  const int m0 = blockIdx.x * 64;

  f32x4 acc[4][3];
#pragma unroll
  for (int mf = 0; mf < 4; ++mf)
#pragma unroll
    for (int nf = 0; nf < 3; ++nf) acc[mf][nf] = (f32x4)0.0f;

  const char* gb0;
  const char* gb1;
  const char* gb2;
  const char* gb3;
  {
    const int rr = l >> 4;
    const int cb = (l & 15) * 16;
    gb0 = (const char*)(x + (size_t)(m0 + 16 * w + 0 + rr) * 1024) + (cb ^ (((0 + rr) & 7) << 4));
    gb1 = (const char*)(x + (size_t)(m0 + 16 * w + 4 + rr) * 1024) + (cb ^ (((4 + rr) & 7) << 4));
    gb2 = (const char*)(x + (size_t)(m0 + 16 * w + 8 + rr) * 1024) + (cb ^ (((0 + rr) & 7) << 4));
    gb3 = (const char*)(x + (size_t)(m0 + 16 * w + 12 + rr) * 1024) + (cb ^ (((4 + rr) & 7) << 4));
  }

  bf16x8 wf[3][2];
  auto loadw = [&](int kt) {
#pragma unroll
    for (int nf = 0; nf < 3; ++nf) {
      const int colg = w * 48 + nf * 16 + lr;
      const bf16* p = Wt + (colg >> 6) * 65536 + (colg & 63) * 1024 + kt + lg * 8;
      wf[nf][0] = *(const bf16x8*)p;
      wf[nf][1] = *(const bf16x8*)(p + 32);
    }
  };
  auto dma = [&](int t) {
    char* lb = (char*)&xs3[t % 3][16 * w][0];
    const int ko = t * 256;
    GLD16(gb0 + ko, lb + 0 * 1024);
    GLD16(gb1 + ko, lb + 1 * 1024);
    GLD16(gb2 + ko, lb + 2 * 1024);
    GLD16(gb3 + ko, lb + 3 * 1024);
  };

  dma(0);
  dma(1);
  const int sw = (lr & 7) << 4;
#pragma unroll
  for (int t = 0; t < 16; ++t) {
    if (t < 15) {
      asm volatile("s_waitcnt vmcnt(4)" ::: "memory");
    } else {
      asm volatile("s_waitcnt vmcnt(0)" ::: "memory");
    }
    __builtin_amdgcn_sched_barrier(0);
    __builtin_amdgcn_s_barrier();
    __builtin_amdgcn_sched_barrier(0);
    loadw(t * 64);
    if (t < 14) dma(t + 2);
    const char* xb = (const char*)&xs3[t % 3][0][0];
#pragma unroll
    for (int mf = 0; mf < 4; ++mf) {
      const char* rp = xb + (mf * 16 + lr) * 256;
      const f32x4 f0 = *(const f32x4*)(rp + ((lg * 32 + 0) ^ sw));
      const f32x4 f1 = *(const f32x4*)(rp + ((lg * 32 + 16) ^ sw));
      const f32x4 f2 = *(const f32x4*)(rp + (128 + ((lg * 32 + 0) ^ sw)));
      const f32x4 f3 = *(const f32x4*)(rp + (128 + ((lg * 32 + 16) ^ sw)));
      bf16x8 a0, a1;
#pragma unroll
      for (int j = 0; j < 4; ++j) {
        a0[j] = (bf16)f0[j]; a0[4 + j] = (bf16)f1[j];
        a1[j] = (bf16)f2[j]; a1[4 + j] = (bf16)f3[j];
      }
#pragma unroll
      for (int nf = 0; nf < 3; ++nf) {
        acc[mf][nf] = MFMA16(a0, wf[nf][0], acc[mf][nf]);
        acc[mf][nf] = MFMA16(a1, wf[nf][1], acc[mf][nf]);
      }
    }
  }

#pragma unroll
  for (int mf = 0; mf < 4; ++mf) {
#pragma unroll
    for (int nf = 0; nf < 3; ++nf) {
      const int colg = w * 48 + nf * 16 + lr;
      const int mat = colg >> 6, h = colg & 63;
      const int mb = m0 + mf * 16 + lg * 4;
      if (mat == 2) {
        const int b = mb / 320, t = mb % 320;
        bf16x4 o;
#pragma unroll
        for (int r = 0; r < 4; ++r) o[r] = (bf16)acc[mf][nf][r];
        *(bf16x4*)(Vt + ((size_t)b * 64 + h) * 320 + t) = o;
      } else {
        bf16* __restrict__ dst = (mat == 0) ? Kw : Qw;
#pragma unroll
        for (int r = 0; r < 4; ++r) dst[(size_t)(mb + r) * 64 + h] = (bf16)acc[mf][nf][r];
      }
    }
  }
}

// ---------------- Kernel 2: causal attention, two-pass, LDS-staged K/V ----------------
// S^T = mfma(A=K, B=Q): lane holds q-row t=lane&15, s = st*64 + nf*16 + (lane>>4)*4 + r.
// K and V staged once per block (traffic /4 vs per-wave loads); per-tile
// wave-private P staging (2 KB/wave). XOR swizzle ((row&7)<<4) on all tiles.
template <int QT>
__device__ __forceinline__ void attn_impl(
    int b, const bf16* __restrict__ Qw, const bf16* __restrict__ Kw,
    const bf16* __restrict__ Vt, float* __restrict__ out,
    char* Ks, char* Vs, char* Ps) {
  constexpr int NT = QT + 1;  // 64-wide s-tiles
  const int tid = threadIdx.x;
  const int w = tid >> 6, l = tid & 63;
  const int lr = l & 15, lg = l >> 4;
  const int t0 = QT * 64 + w * 16;
  const int tq = t0 + lr;

  // Q as B-fragments (col = q row tq)
  const bf16* qp = Qw + ((size_t)b * 320 + tq) * 64 + lg * 8;
  const bf16x8 bq0 = *(const bf16x8*)qp;
  const bf16x8 bq1 = *(const bf16x8*)(qp + 32);

  // ---- phase 1: S^T, K staged in LDS (block-shared, dbuf, async-split) ----
  f32x4 acc[NT * 4];
#pragma unroll
  for (int i = 0; i < NT * 4; ++i) acc[i] = (f32x4)0.0f;

  bf16x8 kg0, kg1;
  const int krow = w * 16 + (l >> 2);  // this lane's staging row (0..63)
  const int kcb = (l & 3) * 16;        // 16B chunk within first 64B half
  const int ksw = (krow & 7) << 4;
  auto gloadK = [&](int st) {
    const bf16* src = Kw + ((size_t)b * 320 + st * 64 + krow) * 64 + (l & 3) * 8;
    kg0 = *(const bf16x8*)src;
    kg1 = *(const bf16x8*)(src + 32);
  };
  auto dswriteK = [&](int buf) {
    char* base = Ks + buf * 8192 + krow * 128;
    *(bf16x8*)(base + (kcb ^ ksw)) = kg0;
    *(bf16x8*)(base + ((kcb + 64) ^ ksw)) = kg1;
  };

  gloadK(0);
  dswriteK(0);
  asm volatile("s_waitcnt lgkmcnt(0)" ::: "memory");
  __builtin_amdgcn_s_barrier();

  const int asw = (lr & 7) << 4;
#pragma unroll
  for (int st = 0; st < NT; ++st) {
    if (st < QT) gloadK(st + 1);  // issue early: HBM latency hides under MFMA
    const char* kb = Ks + (st & 1) * 8192;
#pragma unroll
    for (int nf = 0; nf < 4; ++nf) {
      const char* rp = kb + (nf * 16 + lr) * 128;
      const bf16x8 a0 = *(const bf16x8*)(rp + ((lg * 16) ^ asw));
      const bf16x8 a1 = *(const bf16x8*)(rp + ((64 + lg * 16) ^ asw));
      acc[st * 4 + nf] = MFMA16(a0, bq0, acc[st * 4 + nf]);
      acc[st * 4 + nf] = MFMA16(a1, bq1, acc[st * 4 + nf]);
    }
    if (st < QT) {
      // write other buffer; all waves finished reading it at st-1 (barrier there)
      dswriteK((st + 1) & 1);
      asm volatile("s_waitcnt lgkmcnt(0)" ::: "memory");
      __builtin_amdgcn_s_barrier();
    }
  }

  // issue first V tile loads now: latency hides under softmax VALU
  uint2 vg[4];
  const int vrow = w * 16 + (l >> 4);  // base h-row (step 4)
  auto gloadV = [&](int st) {
    const bf16* src = Vt + ((size_t)b * 64 + vrow) * 320 + st * 64 + (l & 15) * 4;
#pragma unroll
    for (int i = 0; i < 4; ++i) vg[i] = *(const uint2*)(src + i * 4 * 320);
  };
  auto dswriteV = [&](int buf) {
#pragma unroll
    for (int i = 0; i < 4; ++i) {
      const int hl = vrow + i * 4;
      *(uint2*)(Vs + buf * 8192 + hl * 128 + (((l & 15) * 8) ^ ((hl & 7) << 4))) = vg[i];
    }
  };
  gloadV(0);

  // ---- softmax: scale 1/32, causal mask, full row in registers ----
  float mx = -1e30f;
#pragma unroll
  for (int st = 0; st < NT; ++st)
#pragma unroll
    for (int nf = 0; nf < 4; ++nf)
#pragma unroll
      for (int r = 0; r < 4; ++r) {
        const int sg = st * 64 + nf * 16 + lg * 4 + r;
        float v = acc[st * 4 + nf][r] * 0.03125f;
        v = (sg > tq) ? -1e30f : v;
        acc[st * 4 + nf][r] = v;
        mx = fmaxf(mx, v);
      }
  mx = fmaxf(mx, __shfl_xor(mx, 16));
  mx = fmaxf(mx, __shfl_xor(mx, 32));
  float sum = 0.f;
#pragma unroll
  for (int i = 0; i < NT * 4; ++i)
#pragma unroll
    for (int r = 0; r < 4; ++r) {
      const float p = __expf(acc[i][r] - mx);
      acc[i][r] = p;
      sum += p;
    }
  sum += __shfl_xor(sum, 16);
  sum += __shfl_xor(sum, 32);
  const float rinv = 1.0f / sum;

  // ---- phase 2: O = P V, V staged in LDS (dbuf), P via wave-private LDS ----
  dswriteV(0);
  asm volatile("s_waitcnt lgkmcnt(0)" ::: "memory");
  __builtin_amdgcn_s_barrier();

  char* Pw = Ps + w * 2048;  // [16 t][128 B] swizzled, wave-private (no barriers)
  f32x4 ao[4];
#pragma unroll
  for (int hf = 0; hf < 4; ++hf) ao[hf] = (f32x4)0.0f;

#pragma unroll
  for (int st = 0; st < NT; ++st) {
    if (st < QT) gloadV(st + 1);
    // normalized P-tile -> wave-private LDS (b64, swizzled)
#pragma unroll
    for (int nf = 0; nf < 4; ++nf) {
      bf16x4 o;
#pragma unroll
      for (int r = 0; r < 4; ++r) o[r] = (bf16)(acc[st * 4 + nf][r] * rinv);
      *(bf16x4*)(Pw + lr * 128 + ((nf * 32 + lg * 8) ^ asw)) = o;
    }
    const char* vb = Vs + (st & 1) * 8192;
#pragma unroll
    for (int ks = 0; ks < 2; ++ks) {
      const bf16x8 ap = *(const bf16x8*)(Pw + lr * 128 + ((ks * 64 + lg * 16) ^ asw));
#pragma unroll
      for (int hf = 0; hf < 4; ++hf) {
        const bf16x8 bv =
            *(const bf16x8*)(vb + (hf * 16 + lr) * 128 + ((ks * 64 + lg * 16) ^ asw));
        ao[hf] = MFMA16(ap, bv, ao[hf]);
      }
    }
    if (st < QT) {
      dswriteV((st + 1) & 1);
      asm volatile("s_waitcnt lgkmcnt(0)" ::: "memory");
      __builtin_amdgcn_s_barrier();
    }
  }

  const int rowb = t0 + lg * 4;
#pragma unroll
  for (int hf = 0; hf < 4; ++hf)
#pragma unroll
    for (int r = 0; r < 4; ++r)
      out[((size_t)b * 320 + rowb + r) * 64 + hf * 16 + lr] = ao[hf][r];
}

__global__ __launch_bounds__(256) void attn_kernel(
    const bf16* __restrict__ Qw, const bf16* __restrict__ Kw,
    const bf16* __restrict__ Vt, float* __restrict__ out) {
  __shared__ __align__(16) char Ks[2 * 8192];
  __shared__ __align__(16) char Vs[2 * 8192];
  __shared__ __align__(16) char Ps[4 * 2048];
  const int b = blockIdx.x;       // id%8 == b%8: all qt of b on one XCD
  const int qt = 4 - blockIdx.y;  // heavy blocks dispatch first
  switch (qt) {
    case 0: attn_impl<0>(b, Qw, Kw, Vt, out, Ks, Vs, Ps); break;
    case 1: attn_impl<1>(b, Qw, Kw, Vt, out, Ks, Vs, Ps); break;
    case 2: attn_impl<2>(b, Qw, Kw, Vt, out, Ks, Vs, Ps); break;
    case 3: attn_impl<3>(b, Qw, Kw, Vt, out, Ks, Vs, Ps); break;
    default: attn_impl<4>(b, Qw, Kw, Vt, out, Ks, Vs, Ps); break;
  }
}

extern "C" void kernel_launch(void* const* d_in, const int* in_sizes, int n_in,
                              void* d_out, int out_size, void* d_ws, size_t ws_size,
                              hipStream_t stream) {
  const float* x  = (const float*)d_in[0];
  const float* Wk = (const float*)d_in[1];
  const float* Wq = (const float*)d_in[2];
  const float* Wv = (const float*)d_in[3];
  float* out = (float*)d_out;

  bf16* Wt = (bf16*)d_ws;
  bf16* Qw = Wt + 3 * 64 * 1024;
  bf16* Kw = Qw + (size_t)81920 * 64;
  bf16* Vt = Kw + (size_t)81920 * 64;

  hipLaunchKernelGGL(wtrans_kernel, dim3(48), dim3(256), 0, stream, Wk, Wq, Wv, Wt);
  hipLaunchKernelGGL(qkv_kernel, dim3(1280), dim3(256), 0, stream, x, Wt, Qw, Kw, Vt);
  hipLaunchKernelGGL(attn_kernel, dim3(256, 5), dim3(256), 0, stream, Qw, Kw, Vt, out);
}